// Round 20
// baseline (520.243 us; speedup 1.0000x reference)
//
#include <hip/hip_runtime.h>
#include <stdint.h>

#define BATCH 32768
#define TT    25

typedef float f32x4 __attribute__((ext_vector_type(4)));
typedef short s16x8 __attribute__((ext_vector_type(8)));

// fc1w|fc2w|fc3w concatenated, bf16, row-major [384][1600]
__device__ __align__(16) short g_Wc[384 * 1600];

#define LOG2E 1.442695040888963f

__device__ __forceinline__ uint32_t f2bf(float v){
  uint32_t u = __float_as_uint(v);
  return (u + 0x7fffu + ((u >> 16) & 1u)) >> 16;   // RNE
}
__device__ __forceinline__ short f2bfs(float v){ return (short)f2bf(v); }

// lane^1 exchange via DPP quad_perm [1,0,3,2] -- 1 VALU op (R18: -12us vs
// __shfl_xor which lowers through the LDS pipe). No operand constraints.
__device__ __forceinline__ int dpp_swap1(int v){
  return __builtin_amdgcn_mov_dpp(v, 0xB1, 0xF, 0xF, true);
}

__device__ __forceinline__ float sigm(float x){
  float e = __builtin_amdgcn_exp2f(-LOG2E * x);
  return __builtin_amdgcn_rcpf(1.0f + e);
}
__device__ __forceinline__ float tanh_(float x){
  float e = __builtin_amdgcn_exp2f(-2.0f*LOG2E * x);
  return 2.0f*__builtin_amdgcn_rcpf(1.0f + e) - 1.0f;
}
// bit-twiddle RNE pack (no asm operand constraints -> regalloc-safe)
__device__ __forceinline__ s16x8 pack8(float4 a, float4 b){
  s16x8 v;
  v[0]=f2bfs(a.x); v[1]=f2bfs(a.y); v[2]=f2bfs(a.z); v[3]=f2bfs(a.w);
  v[4]=f2bfs(b.x); v[5]=f2bfs(b.y); v[6]=f2bfs(b.z); v[7]=f2bfs(b.w);
  return v;
}

// lgkm-only barrier (R17): waits LDS traffic, not outstanding global stores.
__device__ __forceinline__ void barrier_lds_only(){
  asm volatile("s_waitcnt lgkmcnt(0)\n\ts_barrier" ::: "memory");
}

// ---------------- prologue: convert FC weights to bf16 ----------------
__global__ void conv_wc_kernel(const float* __restrict__ fc1w,
                               const float* __restrict__ fc2w,
                               const float* __restrict__ fc3w){
  const int j = blockIdx.x;
  const float* src = (j < 128) ? fc1w + j*1600
                   : (j < 256) ? fc2w + (j-128)*1600
                               : fc3w + (j-256)*1600;
  for (int k = threadIdx.x; k < 1600; k += 256)
    g_Wc[j*1600 + k] = f2bfs(src[k]);
}

// ---------------- FUSED kernel: LSTM x2 + FC GEMM + heads --------------------
// R20 fusion: fc = sum_t h1[t] @ Wc[:, t*64:+64]^T accumulates per-timestep,
// and L1's kt2,3 A-frags ARE the h1[t-1] tile fc chunk t-1 needs -> fc costs
// only 12 L2 loads + 24 MFMAs per wave/phase, independent of the recurrence
// chain (fills the ~45% stall time). Eliminates the fc kernel, the 210MB flat
// HBM round-trip, and the flat stores.
// Register plan (arch must stay <=128, R6/R14 quantum evidence): W1f -> LDS
// (64KB; 1 block/CU resident so LDS is free) frees 64 regs for acc_fc[2][6]
// (48, accumulator-typed). LDS: W1 64KB (aliased by R 48KB post-loop) +
// h-exchange 32KB = 96KB.
__global__ __launch_bounds__(512, 1) void lstm2fc_kernel(
    const float* __restrict__ x,
    const float* __restrict__ wih0, const float* __restrict__ whh0,
    const float* __restrict__ bih0, const float* __restrict__ bhh0,
    const float* __restrict__ wih1, const float* __restrict__ whh1,
    const float* __restrict__ bih1, const float* __restrict__ bhh1,
    const float* __restrict__ fc1b, const float* __restrict__ fc2b, const float* __restrict__ fc3b,
    const float* __restrict__ l1w,  const float* __restrict__ l1b,
    const float* __restrict__ l2w,  const float* __restrict__ l2b,
    const float* __restrict__ l3w,  const float* __restrict__ l3b,
    float* __restrict__ out)
{
  __shared__ char LDSb[98304];
  char* const W1b = LDSb;            // 64KB: W1 rows [256][128k] bf16, swizzled
  char* const Ab  = LDSb + 65536;    // 32KB: h0[0],h0[1],h1[0],h1[1] [64s][64u]
  char* const Rb  = LDSb;            // 48KB R, ALIASES W1 (dead after t-loop)

  const int tid  = threadIdx.x;
  const int lane = tid & 63;
  const int wv   = tid >> 6;
  const int w4   = wv & 3;          // unit group (lstm) / handled in fc cols
  const int wg   = wv >> 2;         // sample half
  const int lrow = lane & 15;
  const int lk   = lane >> 4;
  const int sw   = (lrow & 7) << 4;
  const int sb   = blockIdx.x * 64;
  const int u    = w4*16 + lrow;

  // ---- stage W1 to LDS (R4-verified gate-remapped swizzled layout) ----
  if (tid < 256){
    const int n   = tid;
    const int g   = ((n>>4)&3)*64 + (n>>6)*16 + (n&15);
    const int nsw = (n & 7) << 4;
    const float* r0 = wih1 + g*64;   // k 0..63  (h0 input)
    #pragma unroll
    for (int c = 0; c < 8; c++){
      *(s16x8*)(W1b + ((n*256 + c*16) ^ nsw)) =
        pack8(*(const float4*)(r0 + c*8), *(const float4*)(r0 + c*8 + 4));
    }
    const float* r1 = whh1 + g*64;   // k 64..127 (h1 recurrent)
    #pragma unroll
    for (int c = 0; c < 8; c++){
      *(s16x8*)(W1b + ((n*256 + 128 + c*16) ^ nsw)) =
        pack8(*(const float4*)(r1 + c*8), *(const float4*)(r1 + c*8 + 4));
    }
  }
  // ---- zero h0buf[1] (Ab+8192..16383) and h1buf[1] (Ab+24576..32767) ----
  {
    s16x8 z = {0,0,0,0,0,0,0,0};
    int idx = tid * 32;
    char* pz = Ab + ((idx < 8192) ? 8192 + idx : 16384 + idx);
    *(s16x8*)pz = z; *(s16x8*)(pz + 16) = z;
  }

  // ---- W0 register B-fragments ----
  s16x8 B0x[4], B0h[4][2];
  #pragma unroll
  for (int n = 0; n < 4; n++){
    const int g = n*64 + u;
    if (lk < 2){
      const float* src = wih0 + g*16 + lk*8;
      B0x[n] = pack8(*(const float4*)src, *(const float4*)(src+4));
    } else {
      s16x8 z = {0,0,0,0,0,0,0,0}; B0x[n] = z;
    }
    #pragma unroll
    for (int kt = 0; kt < 2; kt++){
      const float* src = whh0 + g*64 + kt*32 + lk*8;
      B0h[n][kt] = pack8(*(const float4*)src, *(const float4*)(src+4));
    }
  }

  // ---- lstm biases ----
  float b0v[4], b1v[4];
  #pragma unroll
  for (int n = 0; n < 4; n++){
    b0v[n] = bih0[n*64+u] + bhh0[n*64+u];
    b1v[n] = bih1[n*64+u] + bhh1[n*64+u];
  }

  // ---- fc accumulators (persist whole kernel; wave owns samples wg*32..+32
  //      x fc cols w4*96..+96), bias-initialized ----
  f32x4 accF[2][6];
  #pragma unroll
  for (int n = 0; n < 6; n++){
    int j = w4*96 + n*16 + lrow;
    float bv = (j < 128) ? fc1b[j] : (j < 256) ? fc2b[j-128] : fc3b[j-256];
    #pragma unroll
    for (int m = 0; m < 2; m++){ f32x4 iv = {bv,bv,bv,bv}; accF[m][n] = iv; }
  }

  // ---- x fragment pointers + t=0 prefetch ----
  const float* xbase[2];
  #pragma unroll
  for (int m = 0; m < 2; m++)
    xbase[m] = x + (size_t)(sb + wg*32 + m*16 + lrow)*(TT*16) + (lk&1)*8;
  s16x8 xf[2];
  #pragma unroll
  for (int m = 0; m < 2; m++)
    xf[m] = pack8(*(const float4*)(xbase[m]), *(const float4*)(xbase[m] + 4));

  float c0[2][4], c1[2][4];
  #pragma unroll
  for (int m = 0; m < 2; m++)
    #pragma unroll
    for (int r = 0; r < 4; r++){ c0[m][r] = 0.f; c1[m][r] = 0.f; }

  const char* WcB = (const char*)g_Wc;   // [384][1600] bf16, row=3200B

  __syncthreads();

  #pragma unroll 1
  for (int t = 0; t < TT; t++){
    const int p  = t & 1;
    const int pn = p ^ 1;
    // ======== layer 0: x-tile (regs) + 2 h0-tiles from h0buf[pn] ========
    f32x4 acc[2][4];
    #pragma unroll
    for (int m = 0; m < 2; m++)
      #pragma unroll
      for (int n = 0; n < 4; n++){ f32x4 iv = {b0v[n],b0v[n],b0v[n],b0v[n]}; acc[m][n] = iv; }
    #pragma unroll
    for (int m = 0; m < 2; m++)
      #pragma unroll
      for (int n = 0; n < 4; n++)
        acc[m][n] = __builtin_amdgcn_mfma_f32_16x16x32_bf16(xf[m], B0x[n], acc[m][n], 0, 0, 0);
    #pragma unroll
    for (int kt = 0; kt < 2; kt++){
      s16x8 a[2];
      #pragma unroll
      for (int m = 0; m < 2; m++){
        int row = wg*32 + m*16 + lrow;
        a[m] = *(const s16x8*)(Ab + pn*8192 + row*128 + ((kt*64 + lk*16) ^ sw));
      }
      #pragma unroll
      for (int m = 0; m < 2; m++)
        #pragma unroll
        for (int n = 0; n < 4; n++)
          acc[m][n] = __builtin_amdgcn_mfma_f32_16x16x32_bf16(a[m], B0h[n][kt], acc[m][n], 0, 0, 0);
    }
    short hb[2][4];
    #pragma unroll
    for (int m = 0; m < 2; m++)
      #pragma unroll
      for (int r = 0; r < 4; r++){
        float iv = sigm(acc[m][0][r]);
        float fv = sigm(acc[m][1][r]);
        float gv = tanh_(acc[m][2][r]);
        float ov = sigm(acc[m][3][r]);
        float c  = fmaf(fv, c0[m][r], iv*gv); c0[m][r] = c;
        hb[m][r] = f2bfs(ov * tanh_(c));
      }
    #pragma unroll
    for (int m = 0; m < 2; m++)
      #pragma unroll
      for (int r = 0; r < 4; r++){
        int mine = (int)(uint16_t)hb[m][r];
        int part = dpp_swap1(mine);
        if ((lane & 1) == 0){
          int s_ = wg*32 + m*16 + lk*4 + r;
          uint32_t pk = (uint32_t)mine | ((uint32_t)part << 16);
          *(uint32_t*)(Ab + p*8192 + s_*128 + ((u*2) ^ ((s_&7)<<4))) = pk;
        }
      }
    barrier_lds_only();   // S1: h0[t] (and h1[t-1]) visible

    // ---- fc B-frags group 0 (chunk t-1, kt=0) issued early: L2 latency hides
    //      under the L1 kt0,1 ds_reads+MFMAs below ----
    s16x8 bf0[6], bf1[6];
    if (t >= 1){
      #pragma unroll
      for (int n = 0; n < 6; n++)
        bf0[n] = *(const s16x8*)(WcB + (size_t)(w4*96+n*16+lrow)*3200 + (t-1)*128 + lk*16);
    }

    s16x8 xfn[2];
    if (t + 1 < TT){
      #pragma unroll
      for (int m = 0; m < 2; m++)
        xfn[m] = pack8(*(const float4*)(xbase[m] + (t+1)*16),
                       *(const float4*)(xbase[m] + (t+1)*16 + 4));
    }

    // ======== layer 1 kt0,1: h0buf[p] x W1(LDS) ========
    f32x4 acc1[2][4];
    #pragma unroll
    for (int m = 0; m < 2; m++)
      #pragma unroll
      for (int n = 0; n < 4; n++){ f32x4 iv = {b1v[n],b1v[n],b1v[n],b1v[n]}; acc1[m][n] = iv; }
    #pragma unroll
    for (int kt = 0; kt < 2; kt++){
      s16x8 a[2], b[4];
      #pragma unroll
      for (int m = 0; m < 2; m++){
        int row = wg*32 + m*16 + lrow;
        a[m] = *(const s16x8*)(Ab + p*8192 + row*128 + ((kt*64 + lk*16) ^ sw));
      }
      #pragma unroll
      for (int n = 0; n < 4; n++){
        int n2 = w4*64 + n*16 + lrow;
        b[n] = *(const s16x8*)(W1b + n2*256 + ((kt*64 + lk*16) ^ ((n2&7)<<4)));
      }
      #pragma unroll
      for (int m = 0; m < 2; m++)
        #pragma unroll
        for (int n = 0; n < 4; n++)
          acc1[m][n] = __builtin_amdgcn_mfma_f32_16x16x32_bf16(a[m], b[n], acc1[m][n], 0, 0, 0);
    }
    if (t >= 1){
      #pragma unroll
      for (int n = 0; n < 6; n++)
        bf1[n] = *(const s16x8*)(WcB + (size_t)(w4*96+n*16+lrow)*3200 + (t-1)*128 + 64 + lk*16);
    }
    // ======== layer 1 kt2,3: h1buf[pn] (= h1[t-1]) x W1(LDS) + FC chunk t-1 ====
    #pragma unroll
    for (int kt2 = 0; kt2 < 2; kt2++){
      s16x8 a1f[2], b[4];
      #pragma unroll
      for (int m = 0; m < 2; m++){
        int row = wg*32 + m*16 + lrow;
        a1f[m] = *(const s16x8*)(Ab + 16384 + pn*8192 + row*128 + ((kt2*64 + lk*16) ^ sw));
      }
      #pragma unroll
      for (int n = 0; n < 4; n++){
        int n2 = w4*64 + n*16 + lrow;
        b[n] = *(const s16x8*)(W1b + n2*256 + (((128 + kt2*64) + lk*16) ^ ((n2&7)<<4)));
      }
      #pragma unroll
      for (int m = 0; m < 2; m++)
        #pragma unroll
        for (int n = 0; n < 4; n++)
          acc1[m][n] = __builtin_amdgcn_mfma_f32_16x16x32_bf16(a1f[m], b[n], acc1[m][n], 0, 0, 0);
      if (t >= 1){
        #pragma unroll
        for (int m = 0; m < 2; m++)
          #pragma unroll
          for (int n = 0; n < 6; n++)
            accF[m][n] = __builtin_amdgcn_mfma_f32_16x16x32_bf16(
                a1f[m], (kt2 ? bf1 : bf0)[n], accF[m][n], 0, 0, 0);
      }
    }
    // ---- L1 epilogue -> h1buf[p] (no flat store: fc is fused) ----
    #pragma unroll
    for (int m = 0; m < 2; m++)
      #pragma unroll
      for (int r = 0; r < 4; r++){
        float iv = sigm(acc1[m][0][r]);
        float fv = sigm(acc1[m][1][r]);
        float gv = tanh_(acc1[m][2][r]);
        float ov = sigm(acc1[m][3][r]);
        float c  = fmaf(fv, c1[m][r], iv*gv); c1[m][r] = c;
        hb[m][r] = f2bfs(ov * tanh_(c));
      }
    #pragma unroll
    for (int m = 0; m < 2; m++)
      #pragma unroll
      for (int r = 0; r < 4; r++){
        int mine = (int)(uint16_t)hb[m][r];
        int part = dpp_swap1(mine);
        if ((lane & 1) == 0){
          int s_ = wg*32 + m*16 + lk*4 + r;
          uint32_t pk = (uint32_t)mine | ((uint32_t)part << 16);
          *(uint32_t*)(Ab + 16384 + p*8192 + s_*128 + ((u*2) ^ ((s_&7)<<4))) = pk;
        }
      }
    #pragma unroll
    for (int m = 0; m < 2; m++) xf[m] = xfn[m];
    // next phase's S1 covers all hazards (R11 derivation)
  }

  // ======== final fc chunk (t=24; h1[24] in h1buf[0]) ========
  barrier_lds_only();
  #pragma unroll
  for (int kt2 = 0; kt2 < 2; kt2++){
    s16x8 a1f[2], bf[6];
    #pragma unroll
    for (int n = 0; n < 6; n++)
      bf[n] = *(const s16x8*)(WcB + (size_t)(w4*96+n*16+lrow)*3200 + 24*128 + kt2*64 + lk*16);
    #pragma unroll
    for (int m = 0; m < 2; m++){
      int row = wg*32 + m*16 + lrow;
      a1f[m] = *(const s16x8*)(Ab + 16384 + 0*8192 + row*128 + ((kt2*64 + lk*16) ^ sw));
    }
    #pragma unroll
    for (int m = 0; m < 2; m++)
      #pragma unroll
      for (int n = 0; n < 6; n++)
        accF[m][n] = __builtin_amdgcn_mfma_f32_16x16x32_bf16(a1f[m], bf[n], accF[m][n], 0, 0, 0);
  }

  // ======== ReLU + write R (bf16, swizzled) into Rb (aliases dead W1) ========
  barrier_lds_only();   // all waves done with W1 reads before overwriting
  #pragma unroll
  for (int m = 0; m < 2; m++)
    #pragma unroll
    for (int n = 0; n < 6; n++)
      #pragma unroll
      for (int r = 0; r < 4; r++){
        float v = fmaxf(accF[m][n][r], 0.f);
        int mine = (int)(uint16_t)f2bfs(v);
        int part = dpp_swap1(mine);
        if ((lane & 1) == 0){
          int s_ = wg*32 + m*16 + lk*4 + r;
          int fc = w4*96 + n*16 + lrow;
          uint32_t pk = (uint32_t)mine | ((uint32_t)part << 16);
          *(uint32_t*)(Rb + s_*768 + ((fc*2) ^ ((s_&7)<<4))) = pk;
        }
      }
  __syncthreads();

  // ======== heads: waves 0-5 = (head q, sample-half mh) ========
  if (wv < 6){
    const int q  = wv >> 1;
    const int mh = wv & 1;
    const float* Lw = (q==0) ? l1w : (q==1) ? l2w : l3w;
    const float* Lb = (q==0) ? l1b : (q==1) ? l2b : l3b;
    const int odim  = (q==0) ? 5 : (q==1) ? 4 : 8;
    s16x8 Bh[4];
    #pragma unroll
    for (int kt = 0; kt < 4; kt++){
      if (lrow < odim){
        const float* src = Lw + lrow*128 + kt*32 + lk*8;
        Bh[kt] = pack8(*(const float4*)src, *(const float4*)(src+4));
      } else {
        s16x8 z = {0,0,0,0,0,0,0,0}; Bh[kt] = z;
      }
    }
    float bv = (lrow < odim) ? Lb[lrow] : 0.f;
    f32x4 acc2[2];
    #pragma unroll
    for (int mm = 0; mm < 2; mm++){ f32x4 iv = {bv,bv,bv,bv}; acc2[mm] = iv; }
    #pragma unroll
    for (int kt = 0; kt < 4; kt++){
      s16x8 av[2];
      #pragma unroll
      for (int mm = 0; mm < 2; mm++){
        int row = (mh*2+mm)*16 + lrow;
        av[mm] = *(const s16x8*)(Rb + row*768 + ((q*256 + kt*64 + lk*16) ^ ((row&7)<<4)));
      }
      #pragma unroll
      for (int mm = 0; mm < 2; mm++)
        acc2[mm] = __builtin_amdgcn_mfma_f32_16x16x32_bf16(av[mm], Bh[kt], acc2[mm], 0, 0, 0);
    }
    #pragma unroll
    for (int mm = 0; mm < 2; mm++)
      #pragma unroll
      for (int r = 0; r < 4; r++){
        int smp = sb + (mh*2+mm)*16 + lk*4 + r;
        if (q == 0){
          if (lrow < 5) out[(size_t)smp*5 + lrow] = acc2[mm][r];
        } else if (q == 1){
          if (lrow < 4) out[(size_t)BATCH*5 + (size_t)smp*4 + lrow] = acc2[mm][r];
        } else {
          if (lrow < 8) out[(size_t)BATCH*9 + (size_t)smp*8 + lrow] = acc2[mm][r];
        }
      }
  }
}

extern "C" void kernel_launch(void* const* d_in, const int* in_sizes, int n_in,
                              void* d_out, int out_size, void* d_ws, size_t ws_size,
                              hipStream_t stream)
{
  const float* x    = (const float*)d_in[0];
  const float* wih0 = (const float*)d_in[1];
  const float* whh0 = (const float*)d_in[2];
  const float* bih0 = (const float*)d_in[3];
  const float* bhh0 = (const float*)d_in[4];
  const float* wih1 = (const float*)d_in[5];
  const float* whh1 = (const float*)d_in[6];
  const float* bih1 = (const float*)d_in[7];
  const float* bhh1 = (const float*)d_in[8];
  const float* fc1w = (const float*)d_in[9];
  const float* fc1b = (const float*)d_in[10];
  const float* fc2w = (const float*)d_in[11];
  const float* fc2b = (const float*)d_in[12];
  const float* fc3w = (const float*)d_in[13];
  const float* fc3b = (const float*)d_in[14];
  const float* l1w  = (const float*)d_in[15];
  const float* l1b  = (const float*)d_in[16];
  const float* l2w  = (const float*)d_in[17];
  const float* l2b  = (const float*)d_in[18];
  const float* l3w  = (const float*)d_in[19];
  const float* l3b  = (const float*)d_in[20];

  float* out = (float*)d_out;
  (void)d_ws; (void)ws_size; (void)in_sizes; (void)n_in; (void)out_size;

  conv_wc_kernel<<<dim3(384), dim3(256), 0, stream>>>(fc1w, fc2w, fc3w);

  lstm2fc_kernel<<<dim3(BATCH/64), dim3(512), 0, stream>>>(
      x, wih0, whh0, bih0, bhh0, wih1, whh1, bih1, bhh1,
      fc1b, fc2b, fc3b, l1w, l1b, l2w, l2b, l3w, l3b, out);
}

// Round 21
// 361.570 us; speedup vs baseline: 1.4388x; 1.4388x over previous
//
#include <hip/hip_runtime.h>
#include <stdint.h>

#define BATCH 32768
#define TT    25

typedef float f32x4 __attribute__((ext_vector_type(4)));
typedef short s16x8 __attribute__((ext_vector_type(8)));

// fc1w|fc2w|fc3w concatenated, bf16, row-major [384][1600]
__device__ __align__(16) short g_Wc[384 * 1600];

#define LOG2E 1.442695040888963f

__device__ __forceinline__ uint32_t f2bf(float v){
  uint32_t u = __float_as_uint(v);
  return (u + 0x7fffu + ((u >> 16) & 1u)) >> 16;   // RNE
}
__device__ __forceinline__ short f2bfs(float v){ return (short)f2bf(v); }

// packed f32x2 -> bf16x2 (RNE) via asm. ONLY in fc kernel: in the lstm kernel
// the "v"-constrained asm pushed arch VGPR 128->140 (R6), crossing the register
// quantum (128+64agpr=192 -> 2 waves/SIMD resident; more arch VGPR -> 1).
__device__ __forceinline__ uint32_t cvt_pk_bf16(float lo, float hi){
  uint32_t d;
  asm("v_cvt_pk_bf16_f32 %0, %1, %2" : "=v"(d) : "v"(lo), "v"(hi));
  return d;
}

// lane^1 exchange via DPP quad_perm [1,0,3,2] -- 1 VALU op. R18 MEASURED:
// -12us vs __shfl_xor (which lowers through the LDS pipe, ~120cyc latency).
__device__ __forceinline__ int dpp_swap1(int v){
  return __builtin_amdgcn_mov_dpp(v, 0xB1, 0xF, 0xF, true);
}
__device__ __forceinline__ float dpp_swap1f(float v){
  return __int_as_float(__builtin_amdgcn_mov_dpp(__float_as_int(v), 0xB1, 0xF, 0xF, true));
}

__device__ __forceinline__ float sigm(float x){
  float e = __builtin_amdgcn_exp2f(-LOG2E * x);
  return __builtin_amdgcn_rcpf(1.0f + e);
}
__device__ __forceinline__ float tanh_(float x){
  float e = __builtin_amdgcn_exp2f(-2.0f*LOG2E * x);
  return 2.0f*__builtin_amdgcn_rcpf(1.0f + e) - 1.0f;
}
// bit-twiddle pack (proven regalloc: fits the lstm kernel at 128 arch VGPR)
__device__ __forceinline__ s16x8 pack8(float4 a, float4 b){
  s16x8 v;
  v[0]=f2bfs(a.x); v[1]=f2bfs(a.y); v[2]=f2bfs(a.z); v[3]=f2bfs(a.w);
  v[4]=f2bfs(b.x); v[5]=f2bfs(b.y); v[6]=f2bfs(b.z); v[7]=f2bfs(b.w);
  return v;
}

// Barrier that waits ONLY on LDS traffic (lgkmcnt), not outstanding global
// stores (vmcnt). R17: neutral vs __syncthreads, kept (theoretically cleaner).
__device__ __forceinline__ void barrier_lds_only(){
  asm volatile("s_waitcnt lgkmcnt(0)\n\ts_barrier" ::: "memory");
}

// ---------------- prologue: convert FC weights to bf16 ----------------
__global__ void conv_wc_kernel(const float* __restrict__ fc1w,
                               const float* __restrict__ fc2w,
                               const float* __restrict__ fc3w){
  const int j = blockIdx.x;
  const float* src = (j < 128) ? fc1w + j*1600
                   : (j < 256) ? fc2w + (j-128)*1600
                               : fc3w + (j-256)*1600;
  for (int k = threadIdx.x; k < 1600; k += 256)
    g_Wc[j*1600 + k] = f2bfs(src[k]);
}

// ---------------- Kernel 1: LSTM via MFMA (R18/R19 verified best) ------------
// 512 blocks x 512 threads (8 waves), 64 samples/block, VGPR=128(+64 AGPR) ->
// 1 block/CU (2 waves/SIMD), the register-file optimum. ALL weights in per-wave
// register B-fragments (R5: W1-in-LDS costs 7M bank conflicts; R20 fusion
// re-confirmed); LDS = only the h exchange, double-buffered (32KB); single
// lgkm-only barrier per timestep (R11); DPP lane^1 exchange (R18).
// Final residual: recurrence dep-chain at 2 waves/SIMD; 12 structural probes
// of occupancy/fusion all regressed (R6/7/9/10/13/14/15/20).
__global__ __launch_bounds__(512, 1) void lstm2_mfma_kernel(
    const float* __restrict__ x,
    const float* __restrict__ wih0, const float* __restrict__ whh0,
    const float* __restrict__ bih0, const float* __restrict__ bhh0,
    const float* __restrict__ wih1, const float* __restrict__ whh1,
    const float* __restrict__ bih1, const float* __restrict__ bhh1,
    short* __restrict__ flat)                 // [BATCH][1600] bf16
{
  __shared__ short Abuf[4*64*64];   // 32 KiB: h0[0],h0[1],h1[0],h1[1]; [64s][64u] each
  char* const Ab = (char*)Abuf;     // region r at byte r*8192; row=128B, XOR-swizzled

  const int tid  = threadIdx.x;
  const int lane = tid & 63;
  const int wv   = tid >> 6;
  const int w4   = wv & 3;          // unit group
  const int wg   = wv >> 2;         // sample half
  const int lrow = lane & 15;
  const int lk   = lane >> 4;
  const int sw   = (lrow & 7) << 4;
  const int sb   = blockIdx.x * 64;
  const int u    = w4*16 + lrow;

  // ---- zero h0buf[1], h1buf[1] (read at t=0) ----
  {
    s16x8 z = {0,0,0,0,0,0,0,0};
    int idx = tid * 32;
    char* pz = Ab + ((idx < 8192) ? 8192 + idx : 16384 + idx);
    *(s16x8*)pz = z; *(s16x8*)(pz + 16) = z;
  }

  // ---- ALL weights as register B-fragments ----
  s16x8 W1f[4][4], B0x[4], B0h[4][2];
  #pragma unroll
  for (int n = 0; n < 4; n++){
    const int g = n*64 + u;                       // gate n, unit u
    #pragma unroll
    for (int kt = 0; kt < 4; kt++){
      const float* src = (kt < 2 ? wih1 + g*64 + kt*32 : whh1 + g*64 + (kt-2)*32) + lk*8;
      W1f[n][kt] = pack8(*(const float4*)src, *(const float4*)(src+4));
    }
    if (lk < 2){
      const float* src = wih0 + g*16 + lk*8;
      B0x[n] = pack8(*(const float4*)src, *(const float4*)(src+4));
    } else {
      s16x8 z = {0,0,0,0,0,0,0,0}; B0x[n] = z;
    }
    #pragma unroll
    for (int kt = 0; kt < 2; kt++){
      const float* src = whh0 + g*64 + kt*32 + lk*8;
      B0h[n][kt] = pack8(*(const float4*)src, *(const float4*)(src+4));
    }
  }

  // ---- biases (i,f,g,o for unit u) ----
  float b0v[4], b1v[4];
  #pragma unroll
  for (int n = 0; n < 4; n++){
    b0v[n] = bih0[n*64+u] + bhh0[n*64+u];
    b1v[n] = bih1[n*64+u] + bhh1[n*64+u];
  }

  // ---- x fragment pointers + t=0 prefetch ----
  const float* xbase[2];
  #pragma unroll
  for (int m = 0; m < 2; m++)
    xbase[m] = x + (size_t)(sb + wg*32 + m*16 + lrow)*(TT*16) + (lk&1)*8;
  s16x8 xf[2];
  #pragma unroll
  for (int m = 0; m < 2; m++)
    xf[m] = pack8(*(const float4*)(xbase[m]), *(const float4*)(xbase[m] + 4));

  float c0[2][4], c1[2][4];
  #pragma unroll
  for (int m = 0; m < 2; m++)
    #pragma unroll
    for (int r = 0; r < 4; r++){ c0[m][r] = 0.f; c1[m][r] = 0.f; }

  __syncthreads();   // one-time full barrier after staging

  #pragma unroll 1
  for (int t = 0; t < TT; t++){
    const int p  = t & 1;
    const int pn = p ^ 1;
    // ======== layer 0: x-tile (regs) + 2 h0-tiles from h0buf[pn] ========
    f32x4 acc[2][4];
    #pragma unroll
    for (int m = 0; m < 2; m++)
      #pragma unroll
      for (int n = 0; n < 4; n++){ f32x4 iv = {b0v[n],b0v[n],b0v[n],b0v[n]}; acc[m][n] = iv; }
    #pragma unroll
    for (int m = 0; m < 2; m++)
      #pragma unroll
      for (int n = 0; n < 4; n++)
        acc[m][n] = __builtin_amdgcn_mfma_f32_16x16x32_bf16(xf[m], B0x[n], acc[m][n], 0, 0, 0);
    #pragma unroll
    for (int kt = 0; kt < 2; kt++){
      s16x8 a[2];
      #pragma unroll
      for (int m = 0; m < 2; m++){
        int row = wg*32 + m*16 + lrow;
        a[m] = *(const s16x8*)(Ab + pn*8192 + row*128 + ((kt*64 + lk*16) ^ sw));
      }
      #pragma unroll
      for (int m = 0; m < 2; m++)
        #pragma unroll
        for (int n = 0; n < 4; n++)
          acc[m][n] = __builtin_amdgcn_mfma_f32_16x16x32_bf16(a[m], B0h[n][kt], acc[m][n], 0, 0, 0);
    }
    short hb[2][4];
    #pragma unroll
    for (int m = 0; m < 2; m++)
      #pragma unroll
      for (int r = 0; r < 4; r++){
        float iv = sigm(acc[m][0][r]);
        float fv = sigm(acc[m][1][r]);
        float gv = tanh_(acc[m][2][r]);
        float ov = sigm(acc[m][3][r]);
        float c  = fmaf(fv, c0[m][r], iv*gv); c0[m][r] = c;
        hb[m][r] = f2bfs(ov * tanh_(c));
      }
    // write h0[t] to h0buf[p] (disjoint from h0buf[pn] being read)
    #pragma unroll
    for (int m = 0; m < 2; m++)
      #pragma unroll
      for (int r = 0; r < 4; r++){
        int mine = (int)(uint16_t)hb[m][r];
        int part = dpp_swap1(mine);
        if ((lane & 1) == 0){
          int s_ = wg*32 + m*16 + lk*4 + r;
          uint32_t pk = (uint32_t)mine | ((uint32_t)part << 16);
          *(uint32_t*)(Ab + p*8192 + s_*128 + ((u*2) ^ ((s_&7)<<4))) = pk;
        }
      }
    barrier_lds_only();   // S1 (the ONLY barrier): h0[t] and h1[t-1] visible

    // ======== layer 1: reads h0buf[p] (kt 0,1) + h1buf[pn] (kt 2,3) ========
    // Hazards without an end-of-phase barrier (double-buffered regions):
    //   h1[t] write -> read L1[t+1]: next phase's S1 between.     RAW ok
    //   h0buf[pn] read (pre-S1_t) -> rewritten after S1_{t+1}.    WAR ok
    //   h1buf[pn] read (post-S1_t) -> rewritten after S1_{t+1}.   WAR ok
    s16x8 xfn[2];
    if (t + 1 < TT){
      #pragma unroll
      for (int m = 0; m < 2; m++)
        xfn[m] = pack8(*(const float4*)(xbase[m] + (t+1)*16),
                       *(const float4*)(xbase[m] + (t+1)*16 + 4));
    }
    #pragma unroll
    for (int m = 0; m < 2; m++)
      #pragma unroll
      for (int n = 0; n < 4; n++){ f32x4 iv = {b1v[n],b1v[n],b1v[n],b1v[n]}; acc[m][n] = iv; }
    #pragma unroll
    for (int kt = 0; kt < 4; kt++){
      const int reg = (kt < 2) ? p*8192 : 16384 + pn*8192;
      const int ko  = (kt & 1) * 64;
      s16x8 a[2];
      #pragma unroll
      for (int m = 0; m < 2; m++){
        int row = wg*32 + m*16 + lrow;
        a[m] = *(const s16x8*)(Ab + reg + row*128 + ((ko + lk*16) ^ sw));
      }
      #pragma unroll
      for (int m = 0; m < 2; m++)
        #pragma unroll
        for (int n = 0; n < 4; n++)
          acc[m][n] = __builtin_amdgcn_mfma_f32_16x16x32_bf16(a[m], W1f[n][kt], acc[m][n], 0, 0, 0);
    }
    #pragma unroll
    for (int m = 0; m < 2; m++)
      #pragma unroll
      for (int r = 0; r < 4; r++){
        float iv = sigm(acc[m][0][r]);
        float fv = sigm(acc[m][1][r]);
        float gv = tanh_(acc[m][2][r]);
        float ov = sigm(acc[m][3][r]);
        float c  = fmaf(fv, c1[m][r], iv*gv); c1[m][r] = c;
        hb[m][r] = f2bfs(ov * tanh_(c));
      }
    // write h1[t] to h1buf[p] + flat. Visible to L1[t+1] via next phase's S1.
    // flat stores are fire-and-forget; kernel completion fences them for fc.
    #pragma unroll
    for (int m = 0; m < 2; m++)
      #pragma unroll
      for (int r = 0; r < 4; r++){
        int mine = (int)(uint16_t)hb[m][r];
        int part = dpp_swap1(mine);
        if ((lane & 1) == 0){
          int s_ = wg*32 + m*16 + lk*4 + r;
          uint32_t pk = (uint32_t)mine | ((uint32_t)part << 16);
          *(uint32_t*)(Ab + 16384 + p*8192 + s_*128 + ((u*2) ^ ((s_&7)<<4))) = pk;
          *(uint32_t*)(flat + (size_t)(sb+s_)*1600 + t*64 + u) = pk;
        }
      }
    #pragma unroll
    for (int m = 0; m < 2; m++) xf[m] = xfn[m];
    // no end-of-phase barrier: next phase's S1 covers all hazards (see above)
  }
}

// ---------------- Kernel 2: FC GEMM + MFMA heads (R11/R19 verified best) -----
// 512 blocks x 256 threads (4 waves, 64 samples). R bf16 in swizzled LDS
// (48KB); heads via 3 padded-N MFMA tiles. R12 dbuf neutral, R13 8-wave split
// regressed, R19 DPP exchange neutral-kept, R20 fusion regressed (bank
// conflicts + Wc L2 misses on the recurrence path).
__global__ __launch_bounds__(256,1) void fc_mfma_kernel(
    const short* __restrict__ flat,
    const float* __restrict__ fc1b, const float* __restrict__ fc2b, const float* __restrict__ fc3b,
    const float* __restrict__ l1w,  const float* __restrict__ l1b,
    const float* __restrict__ l2w,  const float* __restrict__ l2b,
    const float* __restrict__ l3w,  const float* __restrict__ l3b,
    float* __restrict__ out)
{
  __shared__ short Rs[64*384];    // 48KB bf16, row=768B, XOR-swizzled
  char* const Rb = (char*)Rs;
  const int tid  = threadIdx.x;
  const int lane = tid & 63;
  const int wv   = tid >> 6;      // wave owns fc cols [96w, 96w+96)
  const int lrow = lane & 15;
  const int lk   = lane >> 4;
  const int sb   = blockIdx.x * 64;

  f32x4 acc[4][6];
  #pragma unroll
  for (int n = 0; n < 6; n++){
    int j = wv*96 + n*16 + lrow;
    float bv = (j < 128) ? fc1b[j] : (j < 256) ? fc2b[j-128] : fc3b[j-256];
    #pragma unroll
    for (int m = 0; m < 4; m++){ f32x4 iv = {bv,bv,bv,bv}; acc[m][n] = iv; }
  }

  const char* Abase = (const char*)(flat + (size_t)sb*1600);
  const char* Bbase = (const char*)g_Wc;
  #pragma unroll 1
  for (int kc = 0; kc < 50; kc++){
    s16x8 a[4], b[6];
    #pragma unroll
    for (int m = 0; m < 4; m++)
      a[m] = *(const s16x8*)(Abase + (size_t)(m*16+lrow)*3200 + kc*64 + lk*16);
    #pragma unroll
    for (int n = 0; n < 6; n++)
      b[n] = *(const s16x8*)(Bbase + (size_t)(wv*96+n*16+lrow)*3200 + kc*64 + lk*16);
    #pragma unroll
    for (int m = 0; m < 4; m++)
      #pragma unroll
      for (int n = 0; n < 6; n++)
        acc[m][n] = __builtin_amdgcn_mfma_f32_16x16x32_bf16(a[m], b[n], acc[m][n], 0, 0, 0);
  }

  // ---- ReLU + write R as bf16 pairs (lane^1 exchange via DPP) ----
  #pragma unroll
  for (int m = 0; m < 4; m++)
    #pragma unroll
    for (int n = 0; n < 6; n++)
      #pragma unroll
      for (int r = 0; r < 4; r++){
        float v  = fmaxf(acc[m][n][r], 0.f);
        float vp = dpp_swap1f(v);
        uint32_t pk = cvt_pk_bf16(v, vp);
        if ((lane & 1) == 0){
          int s_ = m*16 + lk*4 + r;
          int fc = wv*96 + n*16 + lrow;
          *(uint32_t*)(Rb + s_*768 + ((fc*2) ^ ((s_&7)<<4))) = pk;
        }
      }
  __syncthreads();

  // ---- heads as 3 padded-N MFMA tiles (K=128 each) ----
  const float* Lw[3] = {l1w, l2w, l3w};
  const int   odim[3] = {5, 4, 8};
  s16x8 Bh[3][4];
  #pragma unroll
  for (int q = 0; q < 3; q++){
    #pragma unroll
    for (int kt = 0; kt < 4; kt++){
      if (lrow < odim[q]){
        const float* src = Lw[q] + lrow*128 + kt*32 + lk*8;
        Bh[q][kt] = pack8(*(const float4*)src, *(const float4*)(src+4));
      } else {
        s16x8 z = {0,0,0,0,0,0,0,0}; Bh[q][kt] = z;
      }
    }
  }
  f32x4 acc2[4][3];
  {
    float bv0 = (lrow < 5) ? l1b[lrow] : 0.f;
    float bv1 = (lrow < 4) ? l2b[lrow] : 0.f;
    float bv2 = (lrow < 8) ? l3b[lrow] : 0.f;
    #pragma unroll
    for (int m = 0; m < 4; m++){
      f32x4 i0 = {bv0,bv0,bv0,bv0}; acc2[m][0] = i0;
      f32x4 i1 = {bv1,bv1,bv1,bv1}; acc2[m][1] = i1;
      f32x4 i2 = {bv2,bv2,bv2,bv2}; acc2[m][2] = i2;
    }
  }
  #pragma unroll
  for (int q = 0; q < 3; q++){
    #pragma unroll
    for (int kt = 0; kt < 4; kt++){
      s16x8 av[4];
      #pragma unroll
      for (int m = 0; m < 4; m++){
        int row = m*16 + lrow;
        av[m] = *(const s16x8*)(Rb + row*768 + ((q*256 + kt*64 + lk*16) ^ ((row&7)<<4)));
      }
      #pragma unroll
      for (int m = 0; m < 4; m++)
        acc2[m][q] = __builtin_amdgcn_mfma_f32_16x16x32_bf16(av[m], Bh[q][kt], acc2[m][q], 0, 0, 0);
    }
  }
  #pragma unroll
  for (int m = 0; m < 4; m++)
    #pragma unroll
    for (int r = 0; r < 4; r++){
      int smp = sb + m*16 + lk*4 + r;
      if (lrow < 5) out[(size_t)smp*5 + lrow] = acc2[m][0][r];
      if (lrow < 4) out[(size_t)BATCH*5 + (size_t)smp*4 + lrow] = acc2[m][1][r];
      if (lrow < 8) out[(size_t)BATCH*9 + (size_t)smp*8 + lrow] = acc2[m][2][r];
    }
}

extern "C" void kernel_launch(void* const* d_in, const int* in_sizes, int n_in,
                              void* d_out, int out_size, void* d_ws, size_t ws_size,
                              hipStream_t stream)
{
  const float* x    = (const float*)d_in[0];
  const float* wih0 = (const float*)d_in[1];
  const float* whh0 = (const float*)d_in[2];
  const float* bih0 = (const float*)d_in[3];
  const float* bhh0 = (const float*)d_in[4];
  const float* wih1 = (const float*)d_in[5];
  const float* whh1 = (const float*)d_in[6];
  const float* bih1 = (const float*)d_in[7];
  const float* bhh1 = (const float*)d_in[8];
  const float* fc1w = (const float*)d_in[9];
  const float* fc1b = (const float*)d_in[10];
  const float* fc2w = (const float*)d_in[11];
  const float* fc2b = (const float*)d_in[12];
  const float* fc3w = (const float*)d_in[13];
  const float* fc3b = (const float*)d_in[14];
  const float* l1w  = (const float*)d_in[15];
  const float* l1b  = (const float*)d_in[16];
  const float* l2w  = (const float*)d_in[17];
  const float* l2b  = (const float*)d_in[18];
  const float* l3w  = (const float*)d_in[19];
  const float* l3b  = (const float*)d_in[20];

  float* out  = (float*)d_out;
  short* flat = (short*)d_ws;
  if (ws_size < (size_t)BATCH*1600*2) return;

  conv_wc_kernel<<<dim3(384), dim3(256), 0, stream>>>(fc1w, fc2w, fc3w);

  lstm2_mfma_kernel<<<dim3(BATCH/64), dim3(512), 0, stream>>>(
      x, wih0, whh0, bih0, bhh0, wih1, whh1, bih1, bhh1, flat);

  fc_mfma_kernel<<<dim3(BATCH/64), dim3(256), 0, stream>>>(
      flat, fc1b, fc2b, fc3b, l1w, l1b, l2w, l2b, l3w, l3b, out);
}